// Round 4
// baseline (567.041 us; speedup 1.0000x reference)
//
#include <hip/hip_runtime.h>
#include <hip/hip_bf16.h>

// ---------------- degree histogram ----------------
__global__ void deg_kernel(const int* __restrict__ dst, int* __restrict__ cnt, int E) {
    int e = blockIdx.x * 256 + threadIdx.x;
    if (e < E) atomicAdd(&cnt[dst[e]], 1);
}

// ---------------- hierarchical exclusive scan of (cnt[i]+1) -> rowptr ----------------
__global__ void scan1(const int* __restrict__ cnt, int* __restrict__ tmp,
                      int* __restrict__ bsum, int n) {
    __shared__ int s[256];
    int i = blockIdx.x * 256 + threadIdx.x;
    int v = (i < n) ? (cnt[i] + 1) : 0;
    s[threadIdx.x] = v;
    __syncthreads();
    for (int off = 1; off < 256; off <<= 1) {
        int x = (threadIdx.x >= off) ? s[threadIdx.x - off] : 0;
        __syncthreads();
        s[threadIdx.x] += x;
        __syncthreads();
    }
    if (i < n) tmp[i] = s[threadIdx.x];
    if (threadIdx.x == 255) bsum[blockIdx.x] = s[255];
}

__global__ void scan2(int* bsum, int nb) {
    __shared__ int s[256];
    int t = threadIdx.x;
    int v = (t < nb) ? bsum[t] : 0;
    s[t] = v;
    __syncthreads();
    for (int off = 1; off < 256; off <<= 1) {
        int x = (t >= off) ? s[t - off] : 0;
        __syncthreads();
        s[t] += x;
        __syncthreads();
    }
    if (t < nb) bsum[t] = s[t] - v;  // exclusive
}

// scan3 fused with dinv + self-loop CSR entry
__global__ void scan3(const int* __restrict__ tmp, const int* __restrict__ bsum,
                      const int* __restrict__ cnt, int* __restrict__ rowptr,
                      float* __restrict__ dinv, int* __restrict__ col, int n) {
    int i = blockIdx.x * 256 + threadIdx.x;
    if (i < n) {
        int inc = tmp[i] + bsum[blockIdx.x];   // inclusive scan of (cnt+1)
        rowptr[i + 1] = inc;
        int c1 = cnt[i] + 1;
        int r0 = inc - c1;                     // exclusive = rowptr[i]
        dinv[i] = rsqrtf((float)c1);
        col[r0] = i;                           // self-loop occupies slot 0 of row i
        if (i == 0) rowptr[0] = 0;
    }
}

// ---------------- fill CSR with real edges ----------------
__global__ void edgefill(const int* __restrict__ src, const int* __restrict__ dst,
                         const int* __restrict__ rowptr, int* __restrict__ fill,
                         int* __restrict__ col, int E) {
    int e = blockIdx.x * 256 + threadIdx.x;
    if (e < E) {
        int d = dst[e];
        int pos = rowptr[d] + 1 + atomicAdd(&fill[d], 1);
        col[pos] = src[e];
    }
}

// ---------------- prescale: xbuf = dinv ⊙ x0 (row-wise) ----------------
__global__ void prescale(const float* __restrict__ X, const float* __restrict__ dinv,
                         float* __restrict__ Out, int n) {
    int i = blockIdx.x * 256 + threadIdx.x;   // over n*32 float4s
    if (i < n * 32) {
        float d = dinv[i >> 5];
        float4 v = ((const float4*)X)[i];
        v.x *= d; v.y *= d; v.z *= d; v.w *= d;
        ((float4*)Out)[i] = v;
    }
}

// ---------------- fused GCN layer: Out = post( (dinv ⊙ (Â · Xs)) @ W + b ) ----------------
// Uses aggregate-then-transform: A(XW) == (AX)W.  Xs holds dinv-prescaled features x̃,
// so y_n = dinv_n * Σ_{s∈N̂(n)} x̃_s is the normalized aggregation.
// post: relu_scale=1 -> dinv ⊙ relu(.)  (produces next layer's x̃);  0 -> identity (final x).
// Block = 256 threads = 8 nodes x 32 lanes (4 dims/lane). y staged in 4KB LDS;
// GEMM phase streams W from L2 (broadcast-coalesced: all 32 lanes of a node group
// read the same 512B W row; 8 node groups reuse it via L1).
__global__ __launch_bounds__(256) void fused_layer(const float* __restrict__ Xs,
                                                   const float* __restrict__ dinv,
                                                   const int* __restrict__ rowptr,
                                                   const int* __restrict__ col,
                                                   const float* __restrict__ W,
                                                   const float* __restrict__ bias,
                                                   float* __restrict__ Out,
                                                   int n, int relu_scale) {
    __shared__ __align__(16) float ylds[8][128];
    int a = threadIdx.x >> 5;        // node slot 0..7
    int lane = threadIdx.x & 31;
    int t = lane * 4;                // dim offset
    int node = blockIdx.x * 8 + a;
    bool valid = node < n;

    // ---- gather phase: y = dinv_n * sum of prescaled neighbor rows ----
    float ax = 0.f, ay = 0.f, az = 0.f, aw = 0.f;
    if (valid) {
        int beg = rowptr[node], end = rowptr[node + 1];
        int k = beg;
        for (; k + 4 <= end; k += 4) {
            int s0 = col[k], s1 = col[k + 1], s2 = col[k + 2], s3 = col[k + 3];
            float4 h0 = *(const float4*)&Xs[(size_t)s0 * 128 + t];
            float4 h1 = *(const float4*)&Xs[(size_t)s1 * 128 + t];
            float4 h2 = *(const float4*)&Xs[(size_t)s2 * 128 + t];
            float4 h3 = *(const float4*)&Xs[(size_t)s3 * 128 + t];
            ax += (h0.x + h1.x) + (h2.x + h3.x);
            ay += (h0.y + h1.y) + (h2.y + h3.y);
            az += (h0.z + h1.z) + (h2.z + h3.z);
            aw += (h0.w + h1.w) + (h2.w + h3.w);
        }
        for (; k < end; ++k) {
            float4 h = *(const float4*)&Xs[(size_t)col[k] * 128 + t];
            ax += h.x; ay += h.y; az += h.z; aw += h.w;
        }
        float dn = dinv[node];
        ax *= dn; ay *= dn; az *= dn; aw *= dn;
    }
    *(float4*)&ylds[a][t] = make_float4(ax, ay, az, aw);
    __syncthreads();

    // ---- GEMM phase: acc[c] = bias[c] + Σ_k y[a][k] * W[k][c], c = t..t+3 ----
    float4 acc = *(const float4*)&bias[t];
#pragma unroll 4
    for (int k4 = 0; k4 < 128; k4 += 4) {
        float4 yv = *(const float4*)&ylds[a][k4];
        float4 w0 = *(const float4*)&W[(size_t)(k4 + 0) * 128 + t];
        float4 w1 = *(const float4*)&W[(size_t)(k4 + 1) * 128 + t];
        float4 w2 = *(const float4*)&W[(size_t)(k4 + 2) * 128 + t];
        float4 w3 = *(const float4*)&W[(size_t)(k4 + 3) * 128 + t];
        acc.x += yv.x * w0.x + yv.y * w1.x + yv.z * w2.x + yv.w * w3.x;
        acc.y += yv.x * w0.y + yv.y * w1.y + yv.z * w2.y + yv.w * w3.y;
        acc.z += yv.x * w0.z + yv.y * w1.z + yv.z * w2.z + yv.w * w3.z;
        acc.w += yv.x * w0.w + yv.y * w1.w + yv.z * w2.w + yv.w * w3.w;
    }

    if (valid) {
        if (relu_scale) {
            float dn = dinv[node];
            acc.x = fmaxf(acc.x, 0.f) * dn;
            acc.y = fmaxf(acc.y, 0.f) * dn;
            acc.z = fmaxf(acc.z, 0.f) * dn;
            acc.w = fmaxf(acc.w, 0.f) * dn;
        }
        *(float4*)&Out[(size_t)node * 128 + t] = acc;
    }
}

// ---------------- edge decoder: out[e] = dot(X[u], X[v]) ----------------
// 16 lanes per edge, 8 floats per lane (2x float4) -> 4 gathers in flight/lane.
__global__ __launch_bounds__(256) void decoder(const float* __restrict__ X,
                                               const int* __restrict__ eli,
                                               float* __restrict__ out, int EL) {
    int e = blockIdx.x * 16 + (threadIdx.x >> 4);
    int lane = threadIdx.x & 15;
    if (e >= EL) return;
    int u = eli[e], v = eli[EL + e];
    const float4* Xu = (const float4*)&X[(size_t)u * 128 + lane * 8];
    const float4* Xv = (const float4*)&X[(size_t)v * 128 + lane * 8];
    float4 a0 = Xu[0], a1 = Xu[1];
    float4 b0 = Xv[0], b1 = Xv[1];
    float d = a0.x * b0.x + a0.y * b0.y + a0.z * b0.z + a0.w * b0.w
            + a1.x * b1.x + a1.y * b1.y + a1.z * b1.z + a1.w * b1.w;
#pragma unroll
    for (int off = 8; off > 0; off >>= 1) d += __shfl_xor(d, off);
    if (lane == 0) out[e] = d;
}

extern "C" void kernel_launch(void* const* d_in, const int* in_sizes, int n_in,
                              void* d_out, int out_size, void* d_ws, size_t ws_size,
                              hipStream_t stream) {
    const float* x0 = (const float*)d_in[0];
    const float* W1 = (const float*)d_in[1];
    const float* b1 = (const float*)d_in[2];
    const float* W2 = (const float*)d_in[3];
    const float* b2 = (const float*)d_in[4];
    const float* W3 = (const float*)d_in[5];
    const float* b3 = (const float*)d_in[6];
    const int* ei   = (const int*)d_in[7];
    const int* eli  = (const int*)d_in[8];
    float* out = (float*)d_out;

    const int D = 128;
    const int N  = in_sizes[0] / D;
    const int E  = in_sizes[7] / 2;
    const int EL = in_sizes[8] / 2;

    const int* src = ei;        // edge_index[0]
    const int* dst = ei + E;    // edge_index[1]

    // -------- workspace carve-up (256B aligned) --------
    char* ws = (char*)d_ws;
    size_t off = 0;
    auto alloc = [&](size_t bytes) -> void* {
        off = (off + 255) & ~(size_t)255;
        void* p = ws + off;
        off += bytes;
        return p;
    };
    int*   cnt    = (int*)alloc((size_t)2 * N * sizeof(int)); // cnt + fill contiguous
    int*   fill   = cnt + N;
    int*   tmp    = (int*)alloc((size_t)N * sizeof(int));
    int*   bsum   = (int*)alloc(256 * sizeof(int));
    int*   rowptr = (int*)alloc((size_t)(N + 1) * sizeof(int));
    float* dinv   = (float*)alloc((size_t)N * sizeof(float));
    int*   col    = (int*)alloc((size_t)(E + N) * sizeof(int));
    float* xbuf   = (float*)alloc((size_t)N * D * sizeof(float));
    float* hbuf   = (float*)alloc((size_t)N * D * sizeof(float));
    (void)ws_size;

    // zero the two atomic-counter arrays
    hipMemsetAsync(cnt, 0, (size_t)2 * N * sizeof(int), stream);

    int nbN = (N + 255) / 256;
    int nbE = (E + 255) / 256;

    // ---- build degree / dinv / CSR ----
    deg_kernel<<<nbE, 256, 0, stream>>>(dst, cnt, E);
    scan1<<<nbN, 256, 0, stream>>>(cnt, tmp, bsum, N);
    scan2<<<1, 256, 0, stream>>>(bsum, nbN);
    scan3<<<nbN, 256, 0, stream>>>(tmp, bsum, cnt, rowptr, dinv, col, N);
    edgefill<<<nbE, 256, 0, stream>>>(src, dst, rowptr, fill, col, E);

    // ---- prescale input features: xbuf = dinv ⊙ x0 ----
    prescale<<<(N * 32 + 255) / 256, 256, 0, stream>>>(x0, dinv, xbuf, N);

    int fusedGrid = (N + 7) / 8;

    // ---- 3 fused layers (aggregate-then-transform), ping-pong buffers ----
    fused_layer<<<fusedGrid, 256, 0, stream>>>(xbuf, dinv, rowptr, col, W1, b1, hbuf, N, 1);
    fused_layer<<<fusedGrid, 256, 0, stream>>>(hbuf, dinv, rowptr, col, W2, b2, xbuf, N, 1);
    fused_layer<<<fusedGrid, 256, 0, stream>>>(xbuf, dinv, rowptr, col, W3, b3, hbuf, N, 0);

    // ---- decoder ----
    decoder<<<(EL + 15) / 16, 256, 0, stream>>>(hbuf, eli, out, EL);
}

// Round 5
// 442.750 us; speedup vs baseline: 1.2807x; 1.2807x over previous
//
#include <hip/hip_runtime.h>
#include <hip/hip_bf16.h>

// ---------------- degree histogram ----------------
__global__ void deg_kernel(const int* __restrict__ dst, int* __restrict__ cnt, int E) {
    int e = blockIdx.x * 256 + threadIdx.x;
    if (e < E) atomicAdd(&cnt[dst[e]], 1);
}

// ---------------- hierarchical exclusive scan of (cnt[i]+1) -> rowptr ----------------
__global__ void scan1(const int* __restrict__ cnt, int* __restrict__ tmp,
                      int* __restrict__ bsum, int n) {
    __shared__ int s[256];
    int i = blockIdx.x * 256 + threadIdx.x;
    int v = (i < n) ? (cnt[i] + 1) : 0;
    s[threadIdx.x] = v;
    __syncthreads();
    for (int off = 1; off < 256; off <<= 1) {
        int x = (threadIdx.x >= off) ? s[threadIdx.x - off] : 0;
        __syncthreads();
        s[threadIdx.x] += x;
        __syncthreads();
    }
    if (i < n) tmp[i] = s[threadIdx.x];
    if (threadIdx.x == 255) bsum[blockIdx.x] = s[255];
}

__global__ void scan2(int* bsum, int nb) {
    __shared__ int s[256];
    int t = threadIdx.x;
    int v = (t < nb) ? bsum[t] : 0;
    s[t] = v;
    __syncthreads();
    for (int off = 1; off < 256; off <<= 1) {
        int x = (t >= off) ? s[t - off] : 0;
        __syncthreads();
        s[t] += x;
        __syncthreads();
    }
    if (t < nb) bsum[t] = s[t] - v;  // exclusive
}

// scan3 fused with dinv + self-loop CSR entry
__global__ void scan3(const int* __restrict__ tmp, const int* __restrict__ bsum,
                      const int* __restrict__ cnt, int* __restrict__ rowptr,
                      float* __restrict__ dinv, int* __restrict__ col, int n) {
    int i = blockIdx.x * 256 + threadIdx.x;
    if (i < n) {
        int inc = tmp[i] + bsum[blockIdx.x];   // inclusive scan of (cnt+1)
        rowptr[i + 1] = inc;
        int c1 = cnt[i] + 1;
        int r0 = inc - c1;                     // exclusive = rowptr[i]
        dinv[i] = rsqrtf((float)c1);
        col[r0] = i;                           // self-loop occupies slot 0 of row i
        if (i == 0) rowptr[0] = 0;
    }
}

// ---------------- fill CSR with real edges ----------------
// Reuses cnt[] (still holding deg) as the per-row cursor via atomicSub:
// first edge for row d gets slot rowptr[d]+deg, last gets rowptr[d]+1.
// (Slot rowptr[d] is the self-loop.)  scan3 consumed cnt before this runs.
__global__ void edgefill(const int* __restrict__ src, const int* __restrict__ dst,
                         const int* __restrict__ rowptr, int* __restrict__ cnt,
                         int* __restrict__ col, int E) {
    int e = blockIdx.x * 256 + threadIdx.x;
    if (e < E) {
        int d = dst[e];
        int pos = rowptr[d] + atomicSub(&cnt[d], 1);
        col[pos] = src[e];
    }
}

// ---------------- fp32 GEMM: H[N,128] = (X[N,128] @ W[128,128]) * dscale[row] ----------------
// 256 threads, 128x128 tile, 8x8 outputs/thread (rows {4ty..+3, 64+4ty..+3},
// cols {4tx..+3, 64+4tx..+3}).  64 FMAs per 4 ds_read_b128; stride-4 LDS reads
// are 2-way bank-aliased (free).  dinv row-scale folded into the epilogue.
__global__ __launch_bounds__(256) void gemm128(const float* __restrict__ X,
                                               const float* __restrict__ W,
                                               const float* __restrict__ dscale,
                                               float* __restrict__ H, int Nrows) {
    __shared__ __align__(16) float xs[16][132];  // [k][row], +4 pad
    __shared__ __align__(16) float ws[16][128];  // [k][col]
    int tid = threadIdx.x;
    int tx = tid & 15;
    int ty = tid >> 4;
    int row0 = blockIdx.x * 128;
    float acc[8][8] = {};
    for (int k0 = 0; k0 < 128; k0 += 16) {
        {   // stage X tile transposed: xs[kk][r], 128 rows x 16 k
            int r = tid >> 2;             // 0..63
            int j = (tid & 3) * 4;        // k sub-offset
            int gr = row0 + r;
            float4 v = (gr < Nrows) ? *(const float4*)&X[(size_t)gr * 128 + k0 + j]
                                    : make_float4(0.f, 0.f, 0.f, 0.f);
            xs[j + 0][r] = v.x; xs[j + 1][r] = v.y; xs[j + 2][r] = v.z; xs[j + 3][r] = v.w;
            int gr2 = gr + 64;
            float4 u = (gr2 < Nrows) ? *(const float4*)&X[(size_t)gr2 * 128 + k0 + j]
                                     : make_float4(0.f, 0.f, 0.f, 0.f);
            xs[j + 0][r + 64] = u.x; xs[j + 1][r + 64] = u.y;
            xs[j + 2][r + 64] = u.z; xs[j + 3][r + 64] = u.w;
        }
        {   // stage W tile: 16 k x 128 c = 512 float4, direct copy
            const float4* Wv = (const float4*)&W[(size_t)k0 * 128];
            float4* wsv = (float4*)&ws[0][0];
            wsv[tid] = Wv[tid];
            wsv[tid + 256] = Wv[tid + 256];
        }
        __syncthreads();
#pragma unroll
        for (int kk = 0; kk < 16; ++kk) {
            float4 xa = *(float4*)&xs[kk][ty * 4];
            float4 xb = *(float4*)&xs[kk][ty * 4 + 64];
            float4 wa = *(float4*)&ws[kk][tx * 4];
            float4 wb = *(float4*)&ws[kk][tx * 4 + 64];
            float xr[8] = {xa.x, xa.y, xa.z, xa.w, xb.x, xb.y, xb.z, xb.w};
            float wr[8] = {wa.x, wa.y, wa.z, wa.w, wb.x, wb.y, wb.z, wb.w};
#pragma unroll
            for (int i = 0; i < 8; ++i)
#pragma unroll
                for (int j = 0; j < 8; ++j)
                    acc[i][j] += xr[i] * wr[j];
        }
        __syncthreads();
    }
#pragma unroll
    for (int i = 0; i < 8; ++i) {
        int gr = row0 + ((i < 4) ? (ty * 4 + i) : (64 + ty * 4 + i - 4));
        if (gr < Nrows) {
            float s = dscale[gr];
            *(float4*)&H[(size_t)gr * 128 + tx * 4] =
                make_float4(acc[i][0] * s, acc[i][1] * s, acc[i][2] * s, acc[i][3] * s);
            *(float4*)&H[(size_t)gr * 128 + 64 + tx * 4] =
                make_float4(acc[i][4] * s, acc[i][5] * s, acc[i][6] * s, acc[i][7] * s);
        }
    }
}

// ---------------- CSR aggregation: out[n] = relu?(dinv[n]*sum(H'[s]) + b) ----------------
// H' pre-scaled by dinv[row] in the GEMM epilogue.  256 threads = 8 nodes x 32
// lanes (float4/lane).  Unroll-4 -> 4 independent dwordx4 gathers in flight.
__global__ __launch_bounds__(256) void agg_kernel(const float* __restrict__ H,
                                                  const float* __restrict__ dinv,
                                                  const int* __restrict__ rowptr,
                                                  const int* __restrict__ col,
                                                  const float* __restrict__ bias,
                                                  float* __restrict__ out,
                                                  int n, int relu) {
    int node = blockIdx.x * 8 + (threadIdx.x >> 5);
    int t = (threadIdx.x & 31) * 4;
    if (node >= n) return;
    int beg = rowptr[node], end = rowptr[node + 1];
    float ax = 0.f, ay = 0.f, az = 0.f, aw = 0.f;
    int k = beg;
    for (; k + 4 <= end; k += 4) {
        int s0 = col[k], s1 = col[k + 1], s2 = col[k + 2], s3 = col[k + 3];
        float4 h0 = *(const float4*)&H[(size_t)s0 * 128 + t];
        float4 h1 = *(const float4*)&H[(size_t)s1 * 128 + t];
        float4 h2 = *(const float4*)&H[(size_t)s2 * 128 + t];
        float4 h3 = *(const float4*)&H[(size_t)s3 * 128 + t];
        ax += (h0.x + h1.x) + (h2.x + h3.x);
        ay += (h0.y + h1.y) + (h2.y + h3.y);
        az += (h0.z + h1.z) + (h2.z + h3.z);
        aw += (h0.w + h1.w) + (h2.w + h3.w);
    }
    for (; k < end; ++k) {
        float4 h = *(const float4*)&H[(size_t)col[k] * 128 + t];
        ax += h.x; ay += h.y; az += h.z; aw += h.w;
    }
    float dn = dinv[node];
    float4 bv = *(const float4*)&bias[t];
    float4 r = make_float4(ax * dn + bv.x, ay * dn + bv.y,
                           az * dn + bv.z, aw * dn + bv.w);
    if (relu) {
        r.x = fmaxf(r.x, 0.f); r.y = fmaxf(r.y, 0.f);
        r.z = fmaxf(r.z, 0.f); r.w = fmaxf(r.w, 0.f);
    }
    *(float4*)&out[(size_t)node * 128 + t] = r;
}

// ---------------- edge decoder: out[e] = dot(X[u], X[v]) ----------------
// 16 lanes per edge, 8 floats per lane (2x float4) -> 4 gathers in flight/lane.
__global__ __launch_bounds__(256) void decoder(const float* __restrict__ X,
                                               const int* __restrict__ eli,
                                               float* __restrict__ out, int EL) {
    int e = blockIdx.x * 16 + (threadIdx.x >> 4);
    int lane = threadIdx.x & 15;
    if (e >= EL) return;
    int u = eli[e], v = eli[EL + e];
    const float4* Xu = (const float4*)&X[(size_t)u * 128 + lane * 8];
    const float4* Xv = (const float4*)&X[(size_t)v * 128 + lane * 8];
    float4 a0 = Xu[0], a1 = Xu[1];
    float4 b0 = Xv[0], b1 = Xv[1];
    float d = a0.x * b0.x + a0.y * b0.y + a0.z * b0.z + a0.w * b0.w
            + a1.x * b1.x + a1.y * b1.y + a1.z * b1.z + a1.w * b1.w;
#pragma unroll
    for (int off = 8; off > 0; off >>= 1) d += __shfl_xor(d, off);
    if (lane == 0) out[e] = d;
}

extern "C" void kernel_launch(void* const* d_in, const int* in_sizes, int n_in,
                              void* d_out, int out_size, void* d_ws, size_t ws_size,
                              hipStream_t stream) {
    const float* x0 = (const float*)d_in[0];
    const float* W1 = (const float*)d_in[1];
    const float* b1 = (const float*)d_in[2];
    const float* W2 = (const float*)d_in[3];
    const float* b2 = (const float*)d_in[4];
    const float* W3 = (const float*)d_in[5];
    const float* b3 = (const float*)d_in[6];
    const int* ei   = (const int*)d_in[7];
    const int* eli  = (const int*)d_in[8];
    float* out = (float*)d_out;

    const int D = 128;
    const int N  = in_sizes[0] / D;
    const int E  = in_sizes[7] / 2;
    const int EL = in_sizes[8] / 2;

    const int* src = ei;        // edge_index[0]
    const int* dst = ei + E;    // edge_index[1]

    // -------- workspace carve-up (256B aligned) --------
    char* ws = (char*)d_ws;
    size_t off = 0;
    auto alloc = [&](size_t bytes) -> void* {
        off = (off + 255) & ~(size_t)255;
        void* p = ws + off;
        off += bytes;
        return p;
    };
    int*   cnt    = (int*)alloc((size_t)N * sizeof(int));
    int*   tmp    = (int*)alloc((size_t)N * sizeof(int));
    int*   bsum   = (int*)alloc(256 * sizeof(int));
    int*   rowptr = (int*)alloc((size_t)(N + 1) * sizeof(int));
    float* dinv   = (float*)alloc((size_t)N * sizeof(float));
    int*   col    = (int*)alloc((size_t)(E + N) * sizeof(int));
    float* hbuf   = (float*)alloc((size_t)N * D * sizeof(float));
    float* xbuf   = (float*)alloc((size_t)N * D * sizeof(float));
    (void)ws_size;

    // zero the degree counters
    hipMemsetAsync(cnt, 0, (size_t)N * sizeof(int), stream);

    int nbN = (N + 255) / 256;
    int nbE = (E + 255) / 256;

    // ---- build degree / dinv / CSR ----
    deg_kernel<<<nbE, 256, 0, stream>>>(dst, cnt, E);
    scan1<<<nbN, 256, 0, stream>>>(cnt, tmp, bsum, N);
    scan2<<<1, 256, 0, stream>>>(bsum, nbN);
    scan3<<<nbN, 256, 0, stream>>>(tmp, bsum, cnt, rowptr, dinv, col, N);
    edgefill<<<nbE, 256, 0, stream>>>(src, dst, rowptr, cnt, col, E);

    int gemmGrid = (N + 127) / 128;
    int aggGrid  = (N + 7) / 8;

    // ---- layer 1 ----
    gemm128<<<gemmGrid, 256, 0, stream>>>(x0, W1, dinv, hbuf, N);
    agg_kernel<<<aggGrid, 256, 0, stream>>>(hbuf, dinv, rowptr, col, b1, xbuf, N, 1);
    // ---- layer 2 ----
    gemm128<<<gemmGrid, 256, 0, stream>>>(xbuf, W2, dinv, hbuf, N);
    agg_kernel<<<aggGrid, 256, 0, stream>>>(hbuf, dinv, rowptr, col, b2, xbuf, N, 1);
    // ---- layer 3 ----
    gemm128<<<gemmGrid, 256, 0, stream>>>(xbuf, W3, dinv, hbuf, N);
    agg_kernel<<<aggGrid, 256, 0, stream>>>(hbuf, dinv, rowptr, col, b3, xbuf, N, 0);

    // ---- decoder ----
    decoder<<<(EL + 15) / 16, 256, 0, stream>>>(xbuf, eli, out, EL);
}